// Round 7
// baseline (236.156 us; speedup 1.0000x reference)
//
#include <hip/hip_runtime.h>

#define PI_F 3.14159f

// ---------------------------------------------------------------------------
// Kernel A v4 (unchanged — control): per-batch MLP head -> per-channel
// PRE-SCALED affine params. 4 batches/block, 256 threads, 1024 blocks.
// Phase 1 reads pc via LDS ds_read_b128 at a wave-uniform address
// (hardware broadcast). kk ascends 0..255 -> bitwise-identical accumulation.
// params layout: [B][20][8] = (P0..P5, 0, 0):
// ix = P0*X + P1*Y + P2 ; iy = P3*X + P4*Y + P5, grid_sample *9+8.5 scaling
// and the +1 pad shift folded in.
// ---------------------------------------------------------------------------
__global__ __launch_bounds__(256) void params_kernel(
    const float* __restrict__ pc, const float* __restrict__ W1, const float* __restrict__ b1,
    const float* __restrict__ Ws, const float* __restrict__ bs,
    const float* __restrict__ Wr, const float* __restrict__ br,
    const float* __restrict__ Wt, const float* __restrict__ bt,
    float* __restrict__ params)
{
    __shared__ float hbuf[4][260];
    __shared__ float raw[4][80];
    __shared__ __align__(16) float pcs[4][256];

    const int t  = threadIdx.x;
    const int b0 = blockIdx.x * 4;

    #pragma unroll
    for (int g = 0; g < 4; ++g)
        pcs[g][t] = pc[(size_t)(b0 + g) * 256 + t];   // coalesced, 1 dword/thread

    float acc[4];
    #pragma unroll
    for (int g = 0; g < 4; ++g) acc[g] = b1[t];
    __syncthreads();

    const float4* p40 = (const float4*)pcs[0];
    const float4* p41 = (const float4*)pcs[1];
    const float4* p42 = (const float4*)pcs[2];
    const float4* p43 = (const float4*)pcs[3];

    #pragma unroll 4
    for (int k4 = 0; k4 < 64; ++k4) {
        const float* wp = W1 + (size_t)k4 * 1024 + t;   // 4 coalesced rows
        float w0 = wp[0], w1 = wp[256], w2 = wp[512], w3 = wp[768];
        float4 p0 = p40[k4];                 // ds_read_b128, broadcast
        float4 p1 = p41[k4];
        float4 p2 = p42[k4];
        float4 p3 = p43[k4];
        acc[0] = fmaf(p0.x, w0, acc[0]);
        acc[1] = fmaf(p1.x, w0, acc[1]);
        acc[2] = fmaf(p2.x, w0, acc[2]);
        acc[3] = fmaf(p3.x, w0, acc[3]);
        acc[0] = fmaf(p0.y, w1, acc[0]);
        acc[1] = fmaf(p1.y, w1, acc[1]);
        acc[2] = fmaf(p2.y, w1, acc[2]);
        acc[3] = fmaf(p3.y, w1, acc[3]);
        acc[0] = fmaf(p0.z, w2, acc[0]);
        acc[1] = fmaf(p1.z, w2, acc[1]);
        acc[2] = fmaf(p2.z, w2, acc[2]);
        acc[3] = fmaf(p3.z, w2, acc[3]);
        acc[0] = fmaf(p0.w, w3, acc[0]);
        acc[1] = fmaf(p1.w, w3, acc[1]);
        acc[2] = fmaf(p2.w, w3, acc[2]);
        acc[3] = fmaf(p3.w, w3, acc[3]);
    }
    #pragma unroll
    for (int g = 0; g < 4; ++g) hbuf[g][t] = fmaxf(acc[g], 0.0f);
    __syncthreads();

    for (int task = t; task < 320; task += 256) {
        int g   = task / 80;
        int col = task - g * 80;
        const float* Wcol;
        float bias;
        int stride;
        if (col < 20)      { Wcol = Ws + col;        bias = bs[col];      stride = 20; }
        else if (col < 40) { Wcol = Wr + (col - 20); bias = br[col - 20]; stride = 20; }
        else               { Wcol = Wt + (col - 40); bias = bt[col - 40]; stride = 40; }
        const float4* h4 = (const float4*)hbuf[g];
        float a = bias;
        #pragma unroll 4
        for (int k4 = 0; k4 < 64; ++k4) {
            float4 h = h4[k4];
            int k = k4 * 4;
            a = fmaf(h.x, Wcol[k * stride], a);
            a = fmaf(h.y, Wcol[(k + 1) * stride], a);
            a = fmaf(h.z, Wcol[(k + 2) * stride], a);
            a = fmaf(h.w, Wcol[(k + 3) * stride], a);
        }
        raw[g][col] = a;
    }
    __syncthreads();

    for (int task = t; task < 80; task += 256) {
        int g = task / 20;
        int f = task - g * 20;
        float sc  = 2.0f / (1.0f + expf(-raw[g][f]));
        float ang = PI_F * tanhf(raw[g][20 + f]);
        float tx  = tanhf(raw[g][40 + 2 * f]);
        float ty  = tanhf(raw[g][40 + 2 * f + 1]);
        float c = cosf(ang), s = sinf(ang);
        float* o = params + ((size_t)(b0 + g) * 20 + f) * 8;
        o[0] = 9.0f * sc * c;  o[1] = -9.0f * sc * s;  o[2] = fmaf(9.0f, tx, 9.5f);
        o[3] = 9.0f * sc * s;  o[4] =  9.0f * sc * c;  o[5] = fmaf(9.0f, ty, 9.5f);
        o[6] = 0.0f;           o[7] = 0.0f;
    }
}

// ---------------------------------------------------------------------------
// Kernel B v6 (resubmit — round-6 failure was a container/infra error, not
// a kernel error): ONE WAVE owns TWO adjacent channels; zero __syncthreads().
// Rationale: v5 waves were latency-bound (params load + 6 slice loads with
// only ~60 instrs of cover). Two channels/wave doubles the independent
// in-flight work (12 slice loads, 2 blend streams, 2 sample streams) at the
// same total issue count. Block = 128 threads (2 waves) x 2 ch = 4 channels,
// 5 blocks/batch. LDS = 4*448*4 = 7168 B -> 16 blocks/CU x 2 waves = 32/32.
// XCD swizzle groups each batch's 5 blocks on one XCD (shared fmap panels
// -> L2 hits). Second point of each x-pair uses incremental coords
// (ix + P0*dX, <=1 ulp shift; output continuous -> tolerance-safe).
// Stride-21 image (coprime 32 banks), taps {0,1,21,22}.
// ---------------------------------------------------------------------------
__device__ __forceinline__ float samp1(const float* wv, float ix, float iy)
{
    ix = fminf(fmaxf(ix, 0.0f), 19.0f);
    iy = fminf(fmaxf(iy, 0.0f), 19.0f);
    float fx = floorf(ix), fy = floorf(iy);
    float u1 = ix - fx, vv = iy - fy;
    int base = (int)fmaf(fy, 21.0f, fx);          // exact: integer-valued
    const float* s = wv + base;
    float t00 = s[0], t01 = s[1], t10 = s[21], t11 = s[22];
    float u0 = 1.0f - u1, vc = 1.0f - vv;
    return fmaf(fmaf(t01, u1, t00 * u0), vc, fmaf(t11, u1, t10 * u0) * vv);
}

__global__ __launch_bounds__(128, 8) void sample_kernel(
    const float* __restrict__ fmap, const float* __restrict__ params,
    float* __restrict__ out)
{
    __shared__ __align__(16) float lds[4][448];

    const int t    = threadIdx.x;
    const int lane = t & 63;
    const int w    = t >> 6;                      // wave 0..1
    // XCD swizzle (bijective: gridDim.x % 8 == 0): dispatch slot s on XCD
    // s%8 handles orig = (s%8)*cpx + s/8 -> same-batch blocks share an XCD.
    const int cpx  = (int)(gridDim.x >> 3);
    const int bid  = blockIdx.x;
    const int orig = (bid & 7) * cpx + (bid >> 3);
    const int b    = orig / 5;
    const int grp  = orig - b * 5;
    const int c0   = grp * 4 + w * 2;             // this wave: c0, c0+1

    float* wv0 = lds[w * 2];
    float* wv1 = lds[w * 2 + 1];

    // --- params for both channels (wave-uniform addresses, issue first)
    const float* pp = params + ((size_t)b * 20 + c0) * 8;
    const float4 pA0 = *(const float4*)(pp);
    const float2 pB0 = *(const float2*)(pp + 4);
    const float4 pA1 = *(const float4*)(pp + 8);
    const float2 pB1 = *(const float2*)(pp + 12);

    // --- z-blend setup per channel (iz = (40c-19)/38)
    float ew0[2], ew1[2];
    const float* s0p[2];
    const float* s1p[2];
    const float* fb = fmap + (size_t)b * 6480;
    #pragma unroll
    for (int ch = 0; ch < 2; ++ch) {
        int c = c0 + ch;
        float izf = (40.0f * (float)c - 19.0f) * (1.0f / 38.0f);
        float fz0 = floorf(izf);
        int   z0  = (int)fz0;
        float wzB = izf - fz0;
        bool  v0  = (z0 >= 0);
        bool  v1  = (z0 + 1 <= 19);
        ew0[ch] = v0 ? (1.0f - wzB) : 0.0f;
        ew1[ch] = v1 ? wzB : 0.0f;
        s0p[ch] = fb + (v0 ? z0 : 0) * 324;
        s1p[ch] = fb + (v1 ? z0 + 1 : 19) * 324;
    }

    // --- 1) ISSUE all 12 slice loads first (clamped index: unconditional)
    float2 a2[2][3], b2[2][3];
    #pragma unroll
    for (int it = 0; it < 3; ++it) {
        int k  = it * 64 + lane;
        int kc = (k < 162) ? k : 161;
        #pragma unroll
        for (int ch = 0; ch < 2; ++ch) {
            a2[ch][it] = *(const float2*)(s0p[ch] + 2 * kc);
            b2[ch][it] = *(const float2*)(s1p[ch] + 2 * kc);
        }
    }

    // --- 2) zero the 124 pad cells of BOTH images (hides load latency)
    #pragma unroll
    for (int ch = 0; ch < 2; ++ch) {
        float* wv = ch ? wv1 : wv0;
        int i = lane;
        wv[(i < 21) ? i : 378 + i] = 0.0f;
        i = 64 + lane;
        if (i < 124) {
            int idx2;
            if (i < 70) idx2 = 378 + i;
            else {
                int q = i - 70;
                int y = 1 + q / 3;
                int r = q - (q / 3) * 3;
                int x = (r == 0) ? 0 : 18 + r;    // 0, 19, 20
                idx2 = y * 21 + x;
            }
            wv[idx2] = 0.0f;
        }
    }

    // --- 3) blend -> padded interiors (both channels per round)
    #pragma unroll
    for (int it = 0; it < 3; ++it) {
        int k = it * 64 + lane;
        if (k < 162) {
            int y = k / 9;
            int x = 2 * (k - y * 9);
            int base = (y + 1) * 21 + (x + 1);
            wv0[base]     = fmaf(a2[0][it].x, ew0[0], b2[0][it].x * ew1[0]);
            wv0[base + 1] = fmaf(a2[0][it].y, ew0[0], b2[0][it].y * ew1[0]);
            wv1[base]     = fmaf(a2[1][it].x, ew0[1], b2[1][it].x * ew1[1]);
            wv1[base + 1] = fmaf(a2[1][it].y, ew0[1], b2[1][it].y * ew1[1]);
        }
    }

    // --- 4) sample both channels: 162 adjacent-x pairs, dwordx2 stores
    float* ob0 = out + (size_t)b * 6480 + c0 * 324;
    float* ob1 = ob0 + 324;
    const float dix0 = pA0.x * (2.0f / 17.0f), diy0 = pA0.w * (2.0f / 17.0f);
    const float dix1 = pA1.x * (2.0f / 17.0f), diy1 = pA1.w * (2.0f / 17.0f);
    #pragma unroll
    for (int it = 0; it < 3; ++it) {
        int k = it * 64 + lane;
        if (k < 162) {
            int y  = k / 9;
            int x0 = 2 * (k - y * 9);
            float X = (float)x0 * (2.0f / 17.0f) - 1.0f;
            float Y = (float)y  * (2.0f / 17.0f) - 1.0f;
            // channel 0
            float ixa0 = fmaf(pA0.x, X, fmaf(pA0.y, Y, pA0.z));
            float iya0 = fmaf(pA0.w, X, fmaf(pB0.x, Y, pB0.y));
            float r00 = samp1(wv0, ixa0, iya0);
            float r01 = samp1(wv0, ixa0 + dix0, iya0 + diy0);
            *(float2*)(ob0 + y * 18 + x0) = make_float2(r00, r01);
            // channel 1
            float ixa1 = fmaf(pA1.x, X, fmaf(pA1.y, Y, pA1.z));
            float iya1 = fmaf(pA1.w, X, fmaf(pB1.x, Y, pB1.y));
            float r10 = samp1(wv1, ixa1, iya1);
            float r11 = samp1(wv1, ixa1 + dix1, iya1 + diy1);
            *(float2*)(ob1 + y * 18 + x0) = make_float2(r10, r11);
        }
    }
}

extern "C" void kernel_launch(void* const* d_in, const int* in_sizes, int n_in,
                              void* d_out, int out_size, void* d_ws, size_t ws_size,
                              hipStream_t stream)
{
    const float* fmap = (const float*)d_in[0];
    const float* pc   = (const float*)d_in[1];
    const float* W1   = (const float*)d_in[2];
    const float* b1   = (const float*)d_in[3];
    const float* Ws   = (const float*)d_in[4];
    const float* bs   = (const float*)d_in[5];
    const float* Wr   = (const float*)d_in[6];
    const float* br   = (const float*)d_in[7];
    const float* Wt   = (const float*)d_in[8];
    const float* bt   = (const float*)d_in[9];
    float* out    = (float*)d_out;
    float* params = (float*)d_ws;     // B*20*8 floats

    const int B = in_sizes[0] / (20 * 18 * 18);   // 4096

    params_kernel<<<B / 4, 256, 0, stream>>>(pc, W1, b1, Ws, bs, Wr, br, Wt, bt, params);
    sample_kernel<<<B * 5, 128, 0, stream>>>(fmap, params, out);
}

// Round 8
// 234.623 us; speedup vs baseline: 1.0065x; 1.0065x over previous
//
#include <hip/hip_runtime.h>

#define PI_F 3.14159f

// ---------------------------------------------------------------------------
// Kernel A v4 (unchanged — control): per-batch MLP head -> per-channel
// PRE-SCALED affine params. 4 batches/block, 256 threads, 1024 blocks.
// Phase 1 reads pc via LDS ds_read_b128 at a wave-uniform address
// (hardware broadcast). kk ascends 0..255 -> bitwise-identical accumulation.
// params layout: [B][20][8] = (P0..P5, 0, 0):
// ix = P0*X + P1*Y + P2 ; iy = P3*X + P4*Y + P5, grid_sample *9+8.5 scaling
// and the +1 pad shift folded in.
// ---------------------------------------------------------------------------
__global__ __launch_bounds__(256) void params_kernel(
    const float* __restrict__ pc, const float* __restrict__ W1, const float* __restrict__ b1,
    const float* __restrict__ Ws, const float* __restrict__ bs,
    const float* __restrict__ Wr, const float* __restrict__ br,
    const float* __restrict__ Wt, const float* __restrict__ bt,
    float* __restrict__ params)
{
    __shared__ float hbuf[4][260];
    __shared__ float raw[4][80];
    __shared__ __align__(16) float pcs[4][256];

    const int t  = threadIdx.x;
    const int b0 = blockIdx.x * 4;

    #pragma unroll
    for (int g = 0; g < 4; ++g)
        pcs[g][t] = pc[(size_t)(b0 + g) * 256 + t];   // coalesced, 1 dword/thread

    float acc[4];
    #pragma unroll
    for (int g = 0; g < 4; ++g) acc[g] = b1[t];
    __syncthreads();

    const float4* p40 = (const float4*)pcs[0];
    const float4* p41 = (const float4*)pcs[1];
    const float4* p42 = (const float4*)pcs[2];
    const float4* p43 = (const float4*)pcs[3];

    #pragma unroll 4
    for (int k4 = 0; k4 < 64; ++k4) {
        const float* wp = W1 + (size_t)k4 * 1024 + t;   // 4 coalesced rows
        float w0 = wp[0], w1 = wp[256], w2 = wp[512], w3 = wp[768];
        float4 p0 = p40[k4];                 // ds_read_b128, broadcast
        float4 p1 = p41[k4];
        float4 p2 = p42[k4];
        float4 p3 = p43[k4];
        acc[0] = fmaf(p0.x, w0, acc[0]);
        acc[1] = fmaf(p1.x, w0, acc[1]);
        acc[2] = fmaf(p2.x, w0, acc[2]);
        acc[3] = fmaf(p3.x, w0, acc[3]);
        acc[0] = fmaf(p0.y, w1, acc[0]);
        acc[1] = fmaf(p1.y, w1, acc[1]);
        acc[2] = fmaf(p2.y, w1, acc[2]);
        acc[3] = fmaf(p3.y, w1, acc[3]);
        acc[0] = fmaf(p0.z, w2, acc[0]);
        acc[1] = fmaf(p1.z, w2, acc[1]);
        acc[2] = fmaf(p2.z, w2, acc[2]);
        acc[3] = fmaf(p3.z, w2, acc[3]);
        acc[0] = fmaf(p0.w, w3, acc[0]);
        acc[1] = fmaf(p1.w, w3, acc[1]);
        acc[2] = fmaf(p2.w, w3, acc[2]);
        acc[3] = fmaf(p3.w, w3, acc[3]);
    }
    #pragma unroll
    for (int g = 0; g < 4; ++g) hbuf[g][t] = fmaxf(acc[g], 0.0f);
    __syncthreads();

    for (int task = t; task < 320; task += 256) {
        int g   = task / 80;
        int col = task - g * 80;
        const float* Wcol;
        float bias;
        int stride;
        if (col < 20)      { Wcol = Ws + col;        bias = bs[col];      stride = 20; }
        else if (col < 40) { Wcol = Wr + (col - 20); bias = br[col - 20]; stride = 20; }
        else               { Wcol = Wt + (col - 40); bias = bt[col - 40]; stride = 40; }
        const float4* h4 = (const float4*)hbuf[g];
        float a = bias;
        #pragma unroll 4
        for (int k4 = 0; k4 < 64; ++k4) {
            float4 h = h4[k4];
            int k = k4 * 4;
            a = fmaf(h.x, Wcol[k * stride], a);
            a = fmaf(h.y, Wcol[(k + 1) * stride], a);
            a = fmaf(h.z, Wcol[(k + 2) * stride], a);
            a = fmaf(h.w, Wcol[(k + 3) * stride], a);
        }
        raw[g][col] = a;
    }
    __syncthreads();

    for (int task = t; task < 80; task += 256) {
        int g = task / 20;
        int f = task - g * 20;
        float sc  = 2.0f / (1.0f + expf(-raw[g][f]));
        float ang = PI_F * tanhf(raw[g][20 + f]);
        float tx  = tanhf(raw[g][40 + 2 * f]);
        float ty  = tanhf(raw[g][40 + 2 * f + 1]);
        float c = cosf(ang), s = sinf(ang);
        float* o = params + ((size_t)(b0 + g) * 20 + f) * 8;
        o[0] = 9.0f * sc * c;  o[1] = -9.0f * sc * s;  o[2] = fmaf(9.0f, tx, 9.5f);
        o[3] = 9.0f * sc * s;  o[4] =  9.0f * sc * c;  o[5] = fmaf(9.0f, ty, 9.5f);
        o[6] = 0.0f;           o[7] = 0.0f;
    }
}

// ---------------------------------------------------------------------------
// Kernel B v7 = v5 (round-5 best, ONE WAVE = ONE channel, 256-thr blocks,
// zero __syncthreads) + XCD swizzle ONLY. v6's 2-ch/wave restructure
// REGRESSED (VALUBusy 53->38%: longer per-wave dep chains = fewer issuable
// waves); its swizzle WORKED (FETCH 64.5->53.1). Keep the winner, graft the
// proven piece. Block = 4 waves = 4 consecutive channels of one batch;
// 5 blocks/batch share the batch's fmap panel -> same-XCD L2 hits.
// Stride-21 image (coprime 32 banks), taps {0,1,21,22}; 162 adjacent-x
// pairs; dwordx2 loads/stores; load-first for latency hiding.
// LDS = 4*448*4 = 7168 B; 8 blocks/CU (32/32 waves).
// ---------------------------------------------------------------------------
__global__ __launch_bounds__(256, 8) void sample_kernel(
    const float* __restrict__ fmap, const float* __restrict__ params,
    float* __restrict__ out)
{
    __shared__ __align__(16) float lds[4][448];

    const int t    = threadIdx.x;
    const int lane = t & 63;
    const int w    = t >> 6;
    // XCD swizzle (bijective: gridDim.x = 20480 % 8 == 0): dispatch slot s
    // (XCD s%8) handles orig = (s%8)*cpx + s/8 -> same-batch blocks co-XCD.
    const int cpx  = (int)(gridDim.x >> 3);
    const int bid  = blockIdx.x;
    const int orig = (bid & 7) * cpx + (bid >> 3);
    const int b    = orig / 5;
    const int grp  = orig - b * 5;
    const int c    = grp * 4 + w;                 // channel 0..19
    float* wv = lds[w];

    // --- affine params for this channel (issue early; wave-uniform addr)
    const float* pp = params + ((size_t)b * 20 + c) * 8;
    const float4 pA = *(const float4*)pp;
    const float2 pB = *(const float2*)(pp + 4);

    // --- z-blend setup (iz = (40c-19)/38)
    const float izf = (40.0f * (float)c - 19.0f) * (1.0f / 38.0f);
    const float fz0 = floorf(izf);
    const int   z0  = (int)fz0;
    const float wzB = izf - fz0;
    const bool  v0  = (z0 >= 0);
    const bool  v1  = (z0 + 1 <= 19);
    const float ew0 = v0 ? (1.0f - wzB) : 0.0f;
    const float ew1 = v1 ? wzB : 0.0f;
    const float* fb = fmap + (size_t)b * 6480;
    const float* s0 = fb + (v0 ? z0 : 0) * 324;
    const float* s1 = fb + (v1 ? z0 + 1 : 19) * 324;

    // --- 1) ISSUE the 6 slice loads first (clamped index: unconditional,
    //        in-bounds; masked lanes load k=161's data and discard)
    float2 a2[3], b2[3];
    #pragma unroll
    for (int it = 0; it < 3; ++it) {
        int k  = it * 64 + lane;
        int kc = (k < 162) ? k : 161;
        a2[it] = *(const float2*)(s0 + 2 * kc);
        b2[it] = *(const float2*)(s1 + 2 * kc);
    }

    // --- 2) zero the 124 pad cells (latency of (1) hides under this)
    {
        int i = lane;
        int idx = (i < 21) ? i : 378 + i;
        wv[idx] = 0.0f;
        i = 64 + lane;
        if (i < 124) {
            int idx2;
            if (i < 70) idx2 = 378 + i;
            else {
                int q = i - 70;
                int y = 1 + q / 3;
                int r = q - (q / 3) * 3;
                int x = (r == 0) ? 0 : 18 + r;     // 0, 19, 20
                idx2 = y * 21 + x;
            }
            wv[idx2] = 0.0f;
        }
    }

    // --- 3) blend -> padded interior, 2 elems/lane/round
    #pragma unroll
    for (int it = 0; it < 3; ++it) {
        int k = it * 64 + lane;                  // pair index
        if (k < 162) {
            int y = k / 9;
            int x = 2 * (k - y * 9);
            int base = (y + 1) * 21 + (x + 1);
            wv[base]     = fmaf(a2[it].x, ew0, b2[it].x * ew1);
            wv[base + 1] = fmaf(a2[it].y, ew0, b2[it].y * ew1);
        }
    }

    // --- 4) sample 324 points as 162 adjacent-x pairs, dwordx2 stores
    float* ob = out + (size_t)b * 6480 + c * 324;
    #pragma unroll
    for (int it = 0; it < 3; ++it) {
        int k = it * 64 + lane;
        if (k < 162) {
            int y  = k / 9;
            int x0 = 2 * (k - y * 9);
            float Y = (float)y * (2.0f / 17.0f) - 1.0f;
            float r2[2];
            #pragma unroll
            for (int q = 0; q < 2; ++q) {
                float X = (float)(x0 + q) * (2.0f / 17.0f) - 1.0f;
                float ix = fmaf(pA.x, X, fmaf(pA.y, Y, pA.z));
                float iy = fmaf(pA.w, X, fmaf(pB.x, Y, pB.y));
                ix = fminf(fmaxf(ix, 0.0f), 19.0f);
                iy = fminf(fmaxf(iy, 0.0f), 19.0f);
                float fx = floorf(ix), fy = floorf(iy);
                float u1 = ix - fx, vv = iy - fy;
                const float* s = wv + ((int)fy * 21 + (int)fx);
                float t00 = s[0], t01 = s[1], t10 = s[21], t11 = s[22];
                float u0 = 1.0f - u1, vc = 1.0f - vv;
                r2[q] = fmaf(fmaf(t01, u1, t00 * u0), vc,
                             fmaf(t11, u1, t10 * u0) * vv);
            }
            *(float2*)(ob + y * 18 + x0) = make_float2(r2[0], r2[1]);
        }
    }
}

extern "C" void kernel_launch(void* const* d_in, const int* in_sizes, int n_in,
                              void* d_out, int out_size, void* d_ws, size_t ws_size,
                              hipStream_t stream)
{
    const float* fmap = (const float*)d_in[0];
    const float* pc   = (const float*)d_in[1];
    const float* W1   = (const float*)d_in[2];
    const float* b1   = (const float*)d_in[3];
    const float* Ws   = (const float*)d_in[4];
    const float* bs   = (const float*)d_in[5];
    const float* Wr   = (const float*)d_in[6];
    const float* br   = (const float*)d_in[7];
    const float* Wt   = (const float*)d_in[8];
    const float* bt   = (const float*)d_in[9];
    float* out    = (float*)d_out;
    float* params = (float*)d_ws;     // B*20*8 floats

    const int B = in_sizes[0] / (20 * 18 * 18);   // 4096

    params_kernel<<<B / 4, 256, 0, stream>>>(pc, W1, b1, Ws, bs, Wr, br, Wt, bt, params);
    sample_kernel<<<B * 5, 256, 0, stream>>>(fmap, params, out);
}